// Round 5
// baseline (1073.234 us; speedup 1.0000x reference)
//
#include <hip/hip_runtime.h>
#include <math.h>

#define NN   100000
#define NE   1000000
#define CIN  128
#define COUT 64
#define BN_EPS 1e-5f
#define NB    391      // ceil(NN/256) level-1 buckets (dst>>8)
#define NBLK1 128      // blocks per branch in sort phases 1/3
#define CHUNK_E ((NE + NBLK1 - 1) / NBLK1)   // 7813

// ---- workspace layout (4-byte element offsets) ----
// y1b: packed bf16 y1, NN*32 uints (12.8 MB), at 0.
// temp (int2 x NE x 3) = [0, 6M) ints OVERLAPS y1b; all sort kernels finish
// before the first k_gemm1 writes y1b (same stream, ordered).
#define Y1B_OFF    0
#define COL_OFF    6000000                  // 3*NE ints
#define ROWPTR_OFF 9000000                  // 3*(NN+1) ints
#define OFF_OFF    9300016                  // 3*NB*NBLK1 ints (150144)
#define W1P_OFF    9450160                  // 3*CIN*COUT floats
#define C1_OFF     (W1P_OFF + 3*CIN*COUT)
#define INSUM_OFF  (C1_OFF + 3*COUT)
#define INSQ_OFF   (INSUM_OFF + CIN)
#define OSUM_OFF   (INSQ_OFF + CIN)
#define OSQ_OFF    (OSUM_OFF + 3*COUT)
#define SCALE_OFF  (OSQ_OFF + 3*COUT)
#define SHIFT_OFF  (SCALE_OFF + CIN)
#define OBNS_OFF   (SHIFT_OFF + CIN)
#define OBNB_OFF   (OBNS_OFF + 3*COUT)
#define ZERO_OFF   INSUM_OFF
#define ZERO_CNT   (2*CIN + 6*COUT)         // 640 floats

__device__ __forceinline__ unsigned bf16_rne(float f) {
    unsigned u = __float_as_uint(f);
    return (u + 0x7FFFu + ((u >> 16) & 1u)) >> 16;
}

// ---- input BN: per-channel sum/sumsq over nodes ----
__global__ __launch_bounds__(256) void k_in_stats(const float* __restrict__ x,
                                                  float* __restrict__ ws) {
    int tid = blockIdx.x * blockDim.x + threadIdx.x;
    int c = tid & (CIN - 1);
    int r0 = tid >> 7;
    int rstride = (gridDim.x * blockDim.x) >> 7;
    float s = 0.f, ss = 0.f;
    for (int r = r0; r < NN; r += rstride) {
        float v = x[(size_t)r * CIN + c];
        s += v; ss += v * v;
    }
    unsafeAtomicAdd(&ws[INSUM_OFF + c], s);
    unsafeAtomicAdd(&ws[INSQ_OFF + c], ss);
}

__global__ void k_in_finalize(const float* __restrict__ g, const float* __restrict__ b,
                              float* __restrict__ ws) {
    int c = threadIdx.x;   // 128 threads
    float mu  = ws[INSUM_OFF + c] * (1.f / NN);
    float var = ws[INSQ_OFF + c] * (1.f / NN) - mu * mu;
    float sc  = g[c] * rsqrtf(var + BN_EPS);
    ws[SCALE_OFF + c] = sc;
    ws[SHIFT_OFF + c] = b[c] - mu * sc;
}

// fold input-BN scale into W1:  W1'[i][k][o] = scale[k]*W1[i][k][o]
__global__ void k_fold(const float* __restrict__ W1, float* __restrict__ ws) {
    int idx = blockIdx.x * blockDim.x + threadIdx.x;   // < 3*128*64
    int k = (idx >> 6) & (CIN - 1);
    ws[W1P_OFF + idx] = ws[SCALE_OFF + k] * W1[idx];
}

// c1[i][o] = sum_k shift[k]*W1[i][k][o]
__global__ void k_c1(const float* __restrict__ W1, float* __restrict__ ws) {
    int i = blockIdx.x, o = threadIdx.x;   // 3 blocks x 64
    float acc = 0.f;
    for (int k = 0; k < CIN; ++k)
        acc = fmaf(ws[SHIFT_OFF + k], W1[i * CIN * COUT + k * COUT + o], acc);
    ws[C1_OFF + i * COUT + o] = acc;
}

// ---- two-level bucket sort of edges by dst ----
__global__ __launch_bounds__(256) void k_sort_hist(const int* __restrict__ e0,
                                                   const int* __restrict__ e1,
                                                   const int* __restrict__ e2,
                                                   int* __restrict__ wsi) {
    int z = blockIdx.y;
    const int* ei = (z == 0) ? e0 : (z == 1) ? e1 : e2;
    __shared__ int h[NB];
    for (int i = threadIdx.x; i < NB; i += 256) h[i] = 0;
    __syncthreads();
    int beg = blockIdx.x * CHUNK_E;
    int end = min(NE, beg + CHUNK_E);
    for (int e = beg + threadIdx.x; e < end; e += 256)
        atomicAdd(&h[ei[NE + e] >> 8], 1);
    __syncthreads();
    int* off = wsi + OFF_OFF + z * (NB * NBLK1);
    for (int i = threadIdx.x; i < NB; i += 256)
        off[i * NBLK1 + blockIdx.x] = h[i];
}

__global__ __launch_bounds__(1024) void k_sort_scan(int* __restrict__ wsi) {
    int z = blockIdx.x;
    int* off = wsi + OFF_OFF + z * (NB * NBLK1);
    const int TOT = NB * NBLK1;              // 50048
    const int CH = (TOT + 1023) / 1024;      // 49
    __shared__ int sh[1024];
    int t = threadIdx.x;
    int base = t * CH;
    int s = 0;
    for (int i = 0; i < CH; ++i) {
        int idx = base + i;
        if (idx < TOT) s += off[idx];
    }
    sh[t] = s;
    __syncthreads();
    for (int o = 1; o < 1024; o <<= 1) {
        int v = (t >= o) ? sh[t - o] : 0;
        __syncthreads();
        sh[t] += v;
        __syncthreads();
    }
    int run = sh[t] - s;
    for (int i = 0; i < CH; ++i) {
        int idx = base + i;
        if (idx < TOT) {
            int v = off[idx];
            off[idx] = run;
            run += v;
        }
    }
}

__global__ __launch_bounds__(256) void k_sort_scatter(const int* __restrict__ e0,
                                                      const int* __restrict__ e1,
                                                      const int* __restrict__ e2,
                                                      int* __restrict__ wsi) {
    int z = blockIdx.y;
    const int* ei = (z == 0) ? e0 : (z == 1) ? e1 : e2;
    const int* off = wsi + OFF_OFF + z * (NB * NBLK1);
    int2* temp = (int2*)wsi + (size_t)z * NE;
    __shared__ int cur[NB];
    for (int i = threadIdx.x; i < NB; i += 256)
        cur[i] = off[i * NBLK1 + blockIdx.x];
    __syncthreads();
    int beg = blockIdx.x * CHUNK_E;
    int end = min(NE, beg + CHUNK_E);
    for (int e = beg + threadIdx.x; e < end; e += 256) {
        int d = ei[NE + e];
        int s = ei[e];
        int pos = atomicAdd(&cur[d >> 8], 1);
        temp[pos] = make_int2(d, s);
    }
}

__global__ __launch_bounds__(256) void k_bucket(int* __restrict__ wsi) {
    int z = blockIdx.y, bk = blockIdx.x;
    const int* off = wsi + OFF_OFF + z * (NB * NBLK1);
    const int2* temp = (const int2*)wsi + (size_t)z * NE;
    int* col    = wsi + COL_OFF + z * NE;
    int* rowptr = wsi + ROWPTR_OFF + z * (NN + 1);
    int bs = off[bk * NBLK1];
    int be = (bk + 1 < NB) ? off[(bk + 1) * NBLK1] : NE;
    __shared__ int h[256], sc[256], cur[256];
    int t = threadIdx.x;
    h[t] = 0;
    __syncthreads();
    for (int e = bs + t; e < be; e += 256)
        atomicAdd(&h[temp[e].x & 255], 1);
    __syncthreads();
    int v = h[t];
    sc[t] = v;
    __syncthreads();
    for (int o = 1; o < 256; o <<= 1) {
        int u = (t >= o) ? sc[t - o] : 0;
        __syncthreads();
        sc[t] += u;
        __syncthreads();
    }
    int excl = sc[t] - v;
    int gd = bk * 256 + t;
    if (gd <= NN) rowptr[gd] = bs + excl;   // gd==NN lands on empty tail -> NE
    cur[t] = excl;
    __syncthreads();
    for (int e = bs + t; e < be; e += 256) {
        int2 p = temp[e];
        int pos = atomicAdd(&cur[p.x & 255], 1);
        col[bs + pos] = p.y;
    }
}

// y1b = pack_bf16(x @ W1' + c1): word w of node n = (ch w, ch w+32)
__global__ __launch_bounds__(256, 2) void k_gemm1(const float* __restrict__ x,
                                                  float* __restrict__ ws, int br) {
    const float* __restrict__ W1p = ws + W1P_OFF + br * CIN * COUT;
    const float* __restrict__ c1  = ws + C1_OFF + br * COUT;
    unsigned* __restrict__ y1b = (unsigned*)ws + Y1B_OFF;
    int lane = threadIdx.x & 63;
    int wave = (blockIdx.x * blockDim.x + threadIdx.x) >> 6;
    int nw   = (gridDim.x * blockDim.x) >> 6;
    float wk[CIN];
    #pragma unroll
    for (int k = 0; k < CIN; ++k) wk[k] = W1p[k * COUT + lane];
    float c1v = c1[lane];
    for (int n = wave; n < NN; n += nw) {
        const float* __restrict__ xr =
            x + (size_t)__builtin_amdgcn_readfirstlane(n) * CIN;
        float a0 = 0.f, a1 = 0.f, a2 = 0.f, a3 = 0.f;
        #pragma unroll
        for (int k = 0; k < CIN; k += 4) {
            a0 = fmaf(xr[k],     wk[k],     a0);
            a1 = fmaf(xr[k + 1], wk[k + 1], a1);
            a2 = fmaf(xr[k + 2], wk[k + 2], a2);
            a3 = fmaf(xr[k + 3], wk[k + 3], a3);
        }
        float v = (a0 + a1) + (a2 + a3) + c1v;
        float vhi = __shfl(v, (lane & 31) + 32);
        if (lane < 32) {
            unsigned w = bf16_rne(v) | (bf16_rne(vhi) << 16);
            y1b[(size_t)n * 32 + lane] = w;
        }
    }
}

// fused: t = y1[n] + sum_{src} y1[src] (bf16 gather); relu(t+b1) @ W2 + b2
// -> out; accumulate output-BN stats
__global__ __launch_bounds__(256, 4) void k_gather_l2(const float* __restrict__ W2all,
                                                      const float* __restrict__ b1all,
                                                      const float* __restrict__ b2all,
                                                      float* __restrict__ out,
                                                      float* __restrict__ ws, int br) {
    const float* __restrict__ W2 = W2all + br * COUT * COUT;
    const unsigned* __restrict__ y1b = (const unsigned*)ws + Y1B_OFF;
    const int* __restrict__ rowptr = (const int*)ws + ROWPTR_OFF + br * (NN + 1);
    const int* __restrict__ col    = (const int*)ws + COL_OFF + br * NE;
    float* osum = ws + OSUM_OFF + br * COUT;
    float* osq  = ws + OSQ_OFF  + br * COUT;
    int lane = threadIdx.x & 63;
    int w32  = lane & 31;
    unsigned hiMask = (lane >= 32) ? 1u : 0u;
    int wave = (blockIdx.x * blockDim.x + threadIdx.x) >> 6;
    int nw   = (gridDim.x * blockDim.x) >> 6;
    float w2k[COUT];
    #pragma unroll
    for (int j = 0; j < COUT; ++j) w2k[j] = W2[j * COUT + lane];
    float b1v = b1all[br * COUT + lane];
    float b2v = b2all[br * COUT + lane];
    float ls = 0.f, lss = 0.f;
#define XTR(w) __uint_as_float(hiMask ? ((w) & 0xFFFF0000u) : ((w) << 16))
    for (int n = wave; n < NN; n += nw) {
        int nn = __builtin_amdgcn_readfirstlane(n);
        int beg = rowptr[nn], end = rowptr[nn + 1];
        float a0 = XTR(y1b[(size_t)nn * 32 + w32]);
        float a1 = 0.f, a2 = 0.f, a3 = 0.f;
        float a4 = 0.f, a5 = 0.f, a6 = 0.f, a7 = 0.f;
        int j = beg;
        for (; j + 7 < end; j += 8) {
            int c0 = __builtin_amdgcn_readfirstlane(col[j]);
            int c1 = __builtin_amdgcn_readfirstlane(col[j + 1]);
            int c2 = __builtin_amdgcn_readfirstlane(col[j + 2]);
            int c3 = __builtin_amdgcn_readfirstlane(col[j + 3]);
            int c4 = __builtin_amdgcn_readfirstlane(col[j + 4]);
            int c5 = __builtin_amdgcn_readfirstlane(col[j + 5]);
            int c6 = __builtin_amdgcn_readfirstlane(col[j + 6]);
            int c7 = __builtin_amdgcn_readfirstlane(col[j + 7]);
            unsigned u0 = y1b[(size_t)c0 * 32 + w32];
            unsigned u1 = y1b[(size_t)c1 * 32 + w32];
            unsigned u2 = y1b[(size_t)c2 * 32 + w32];
            unsigned u3 = y1b[(size_t)c3 * 32 + w32];
            unsigned u4 = y1b[(size_t)c4 * 32 + w32];
            unsigned u5 = y1b[(size_t)c5 * 32 + w32];
            unsigned u6 = y1b[(size_t)c6 * 32 + w32];
            unsigned u7 = y1b[(size_t)c7 * 32 + w32];
            a0 += XTR(u0); a1 += XTR(u1); a2 += XTR(u2); a3 += XTR(u3);
            a4 += XTR(u4); a5 += XTR(u5); a6 += XTR(u6); a7 += XTR(u7);
        }
        for (; j + 3 < end; j += 4) {
            int c0 = __builtin_amdgcn_readfirstlane(col[j]);
            int c1 = __builtin_amdgcn_readfirstlane(col[j + 1]);
            int c2 = __builtin_amdgcn_readfirstlane(col[j + 2]);
            int c3 = __builtin_amdgcn_readfirstlane(col[j + 3]);
            unsigned u0 = y1b[(size_t)c0 * 32 + w32];
            unsigned u1 = y1b[(size_t)c1 * 32 + w32];
            unsigned u2 = y1b[(size_t)c2 * 32 + w32];
            unsigned u3 = y1b[(size_t)c3 * 32 + w32];
            a0 += XTR(u0); a1 += XTR(u1); a2 += XTR(u2); a3 += XTR(u3);
        }
        for (; j < end; ++j) {
            int c0 = __builtin_amdgcn_readfirstlane(col[j]);
            a0 += XTR(y1b[(size_t)c0 * 32 + w32]);
        }
        float t1 = fmaxf(((a0 + a1) + (a2 + a3)) + ((a4 + a5) + (a6 + a7)) + b1v, 0.f);
        int t1i = __float_as_int(t1);
        float s0 = b2v, s1 = 0.f, s2 = 0.f, s3 = 0.f;
        #pragma unroll
        for (int k = 0; k < COUT; k += 4) {
            s0 = fmaf(__int_as_float(__builtin_amdgcn_readlane(t1i, k)),     w2k[k],     s0);
            s1 = fmaf(__int_as_float(__builtin_amdgcn_readlane(t1i, k + 1)), w2k[k + 1], s1);
            s2 = fmaf(__int_as_float(__builtin_amdgcn_readlane(t1i, k + 2)), w2k[k + 2], s2);
            s3 = fmaf(__int_as_float(__builtin_amdgcn_readlane(t1i, k + 3)), w2k[k + 3], s3);
        }
        float acc = (s0 + s1) + (s2 + s3);
        out[(size_t)nn * COUT + lane] = acc;
        ls += acc; lss += acc * acc;
    }
#undef XTR
    unsafeAtomicAdd(&osum[lane], ls);
    unsafeAtomicAdd(&osq[lane], lss);
}

__global__ void k_obn_final(const float* __restrict__ g, const float* __restrict__ b,
                            float* __restrict__ ws, int br) {
    int o = threadIdx.x;   // 64 threads
    float mu  = ws[OSUM_OFF + br * COUT + o] * (1.f / NN);
    float var = ws[OSQ_OFF  + br * COUT + o] * (1.f / NN) - mu * mu;
    float sc  = g[br * COUT + o] * rsqrtf(var + BN_EPS);
    ws[OBNS_OFF + br * COUT + o] = sc;
    ws[OBNB_OFF + br * COUT + o] = b[br * COUT + o] - mu * sc;
}

// y = tanh(sc[c]*h2 + sh[c]) in-place on d_out section
__global__ __launch_bounds__(256) void k_apply(float* __restrict__ out,
                                               const float* __restrict__ ws, int br) {
    const float* __restrict__ sc = ws + OBNS_OFF + br * COUT;
    const float* __restrict__ sh = ws + OBNB_OFF + br * COUT;
    int idx = blockIdx.x * blockDim.x + threadIdx.x;
    int stride = gridDim.x * blockDim.x;
    const int total = NN * COUT / 4;
    float4* o4 = (float4*)out;
    for (int v = idx; v < total; v += stride) {
        int c = (v & 15) * 4;
        float4 f = o4[v];
        f.x = tanhf(fmaf(f.x, sc[c],     sh[c]));
        f.y = tanhf(fmaf(f.y, sc[c + 1], sh[c + 1]));
        f.z = tanhf(fmaf(f.z, sc[c + 2], sh[c + 2]));
        f.w = tanhf(fmaf(f.w, sc[c + 3], sh[c + 3]));
        o4[v] = f;
    }
}

extern "C" void kernel_launch(void* const* d_in, const int* in_sizes, int n_in,
                              void* d_out, int out_size, void* d_ws, size_t ws_size,
                              hipStream_t stream) {
    const float* x   = (const float*)d_in[0];
    const int*   eip = (const int*)d_in[1];
    const int*   eis = (const int*)d_in[2];
    const int*   eiv = (const int*)d_in[3];
    const float* ig  = (const float*)d_in[4];
    const float* ib  = (const float*)d_in[5];
    const float* W1  = (const float*)d_in[6];
    const float* b1  = (const float*)d_in[7];
    const float* W2  = (const float*)d_in[8];
    const float* b2  = (const float*)d_in[9];
    const float* bng = (const float*)d_in[10];
    const float* bnb = (const float*)d_in[11];
    float* out = (float*)d_out;
    float* ws  = (float*)d_ws;
    int*   wsi = (int*)d_ws;

    hipMemsetAsync(ws + ZERO_OFF, 0, ZERO_CNT * sizeof(float), stream);

    k_in_stats<<<256, 256, 0, stream>>>(x, ws);
    k_in_finalize<<<1, 128, 0, stream>>>(ig, ib, ws);
    k_fold<<<96, 256, 0, stream>>>(W1, ws);
    k_c1<<<3, 64, 0, stream>>>(W1, ws);

    // two-level bucket sort -> CSR for all 3 branches (temp overlaps y1b;
    // all sort kernels complete before the first k_gemm1)
    k_sort_hist<<<dim3(NBLK1, 3), 256, 0, stream>>>(eip, eis, eiv, wsi);
    k_sort_scan<<<3, 1024, 0, stream>>>(wsi);
    k_sort_scatter<<<dim3(NBLK1, 3), 256, 0, stream>>>(eip, eis, eiv, wsi);
    k_bucket<<<dim3(NB, 3), 256, 0, stream>>>(wsi);

    for (int br = 0; br < 3; ++br) {
        k_gemm1<<<1024, 256, 0, stream>>>(x, ws, br);
        k_gather_l2<<<2048, 256, 0, stream>>>(W2, b1, b2,
                                              out + (size_t)br * NN * COUT, ws, br);
        k_obn_final<<<1, 64, 0, stream>>>(bng, bnb, ws, br);
        k_apply<<<2048, 256, 0, stream>>>(out + (size_t)br * NN * COUT, ws, br);
    }
}

// Round 6
// 1067.513 us; speedup vs baseline: 1.0054x; 1.0054x over previous
//
#include <hip/hip_runtime.h>
#include <math.h>

#define NN   100000
#define NE   1000000
#define CIN  128
#define COUT 64
#define BN_EPS 1e-5f
#define NB    391      // ceil(NN/256) level-1 buckets (dst>>8)
#define NBLK1 128      // blocks per branch in sort phases 1/3
#define CHUNK_E ((NE + NBLK1 - 1) / NBLK1)   // 7813

// ---- workspace layout (4-byte element offsets) ----
// y1b: packed bf16 y1, NN*32 uints (12.8 MB), at 0.
// temp (int2 x NE x 3) = [0, 6M) ints OVERLAPS y1b; all sort kernels finish
// before the first k_gemm1 writes y1b (same stream, ordered).
#define Y1B_OFF    0
#define COL_OFF    6000000                  // 3*NE ints
#define ROWPTR_OFF 9000000                  // 3*(NN+1) ints
#define OFF_OFF    9300016                  // 3*NB*NBLK1 ints (150144)
#define W1P_OFF    9450160                  // 3*CIN*COUT floats
#define C1_OFF     (W1P_OFF + 3*CIN*COUT)
#define INSUM_OFF  (C1_OFF + 3*COUT)
#define INSQ_OFF   (INSUM_OFF + CIN)
#define OSUM_OFF   (INSQ_OFF + CIN)
#define OSQ_OFF    (OSUM_OFF + 3*COUT)
#define SCALE_OFF  (OSQ_OFF + 3*COUT)
#define SHIFT_OFF  (SCALE_OFF + CIN)
#define OBNS_OFF   (SHIFT_OFF + CIN)
#define OBNB_OFF   (OBNS_OFF + 3*COUT)
#define ZERO_OFF   INSUM_OFF
#define ZERO_CNT   (2*CIN + 6*COUT)         // 640 floats

__device__ __forceinline__ unsigned bf16_rne(float f) {
    unsigned u = __float_as_uint(f);
    return (u + 0x7FFFu + ((u >> 16) & 1u)) >> 16;
}

// ---- input BN: per-channel sum/sumsq over nodes ----
__global__ __launch_bounds__(256) void k_in_stats(const float* __restrict__ x,
                                                  float* __restrict__ ws) {
    int tid = blockIdx.x * blockDim.x + threadIdx.x;
    int c = tid & (CIN - 1);
    int r0 = tid >> 7;
    int rstride = (gridDim.x * blockDim.x) >> 7;
    float s = 0.f, ss = 0.f;
    for (int r = r0; r < NN; r += rstride) {
        float v = x[(size_t)r * CIN + c];
        s += v; ss += v * v;
    }
    unsafeAtomicAdd(&ws[INSUM_OFF + c], s);
    unsafeAtomicAdd(&ws[INSQ_OFF + c], ss);
}

__global__ void k_in_finalize(const float* __restrict__ g, const float* __restrict__ b,
                              float* __restrict__ ws) {
    int c = threadIdx.x;   // 128 threads
    float mu  = ws[INSUM_OFF + c] * (1.f / NN);
    float var = ws[INSQ_OFF + c] * (1.f / NN) - mu * mu;
    float sc  = g[c] * rsqrtf(var + BN_EPS);
    ws[SCALE_OFF + c] = sc;
    ws[SHIFT_OFF + c] = b[c] - mu * sc;
}

// fold input-BN scale into W1:  W1'[i][k][o] = scale[k]*W1[i][k][o]
__global__ void k_fold(const float* __restrict__ W1, float* __restrict__ ws) {
    int idx = blockIdx.x * blockDim.x + threadIdx.x;   // < 3*128*64
    int k = (idx >> 6) & (CIN - 1);
    ws[W1P_OFF + idx] = ws[SCALE_OFF + k] * W1[idx];
}

// c1[i][o] = sum_k shift[k]*W1[i][k][o]
__global__ void k_c1(const float* __restrict__ W1, float* __restrict__ ws) {
    int i = blockIdx.x, o = threadIdx.x;   // 3 blocks x 64
    float acc = 0.f;
    for (int k = 0; k < CIN; ++k)
        acc = fmaf(ws[SHIFT_OFF + k], W1[i * CIN * COUT + k * COUT + o], acc);
    ws[C1_OFF + i * COUT + o] = acc;
}

// ---- two-level bucket sort of edges by dst ----
__global__ __launch_bounds__(256) void k_sort_hist(const int* __restrict__ e0,
                                                   const int* __restrict__ e1,
                                                   const int* __restrict__ e2,
                                                   int* __restrict__ wsi) {
    int z = blockIdx.y;
    const int* ei = (z == 0) ? e0 : (z == 1) ? e1 : e2;
    __shared__ int h[NB];
    for (int i = threadIdx.x; i < NB; i += 256) h[i] = 0;
    __syncthreads();
    int beg = blockIdx.x * CHUNK_E;
    int end = min(NE, beg + CHUNK_E);
    for (int e = beg + threadIdx.x; e < end; e += 256)
        atomicAdd(&h[ei[NE + e] >> 8], 1);
    __syncthreads();
    int* off = wsi + OFF_OFF + z * (NB * NBLK1);
    for (int i = threadIdx.x; i < NB; i += 256)
        off[i * NBLK1 + blockIdx.x] = h[i];
}

__global__ __launch_bounds__(1024) void k_sort_scan(int* __restrict__ wsi) {
    int z = blockIdx.x;
    int* off = wsi + OFF_OFF + z * (NB * NBLK1);
    const int TOT = NB * NBLK1;              // 50048
    const int CH = (TOT + 1023) / 1024;      // 49
    __shared__ int sh[1024];
    int t = threadIdx.x;
    int base = t * CH;
    int s = 0;
    for (int i = 0; i < CH; ++i) {
        int idx = base + i;
        if (idx < TOT) s += off[idx];
    }
    sh[t] = s;
    __syncthreads();
    for (int o = 1; o < 1024; o <<= 1) {
        int v = (t >= o) ? sh[t - o] : 0;
        __syncthreads();
        sh[t] += v;
        __syncthreads();
    }
    int run = sh[t] - s;
    for (int i = 0; i < CH; ++i) {
        int idx = base + i;
        if (idx < TOT) {
            int v = off[idx];
            off[idx] = run;
            run += v;
        }
    }
}

__global__ __launch_bounds__(256) void k_sort_scatter(const int* __restrict__ e0,
                                                      const int* __restrict__ e1,
                                                      const int* __restrict__ e2,
                                                      int* __restrict__ wsi) {
    int z = blockIdx.y;
    const int* ei = (z == 0) ? e0 : (z == 1) ? e1 : e2;
    const int* off = wsi + OFF_OFF + z * (NB * NBLK1);
    int2* temp = (int2*)wsi + (size_t)z * NE;
    __shared__ int cur[NB];
    for (int i = threadIdx.x; i < NB; i += 256)
        cur[i] = off[i * NBLK1 + blockIdx.x];
    __syncthreads();
    int beg = blockIdx.x * CHUNK_E;
    int end = min(NE, beg + CHUNK_E);
    for (int e = beg + threadIdx.x; e < end; e += 256) {
        int d = ei[NE + e];
        int s = ei[e];
        int pos = atomicAdd(&cur[d >> 8], 1);
        temp[pos] = make_int2(d, s);
    }
}

__global__ __launch_bounds__(256) void k_bucket(int* __restrict__ wsi) {
    int z = blockIdx.y, bk = blockIdx.x;
    const int* off = wsi + OFF_OFF + z * (NB * NBLK1);
    const int2* temp = (const int2*)wsi + (size_t)z * NE;
    int* col    = wsi + COL_OFF + z * NE;
    int* rowptr = wsi + ROWPTR_OFF + z * (NN + 1);
    int bs = off[bk * NBLK1];
    int be = (bk + 1 < NB) ? off[(bk + 1) * NBLK1] : NE;
    __shared__ int h[256], sc[256], cur[256];
    int t = threadIdx.x;
    h[t] = 0;
    __syncthreads();
    for (int e = bs + t; e < be; e += 256)
        atomicAdd(&h[temp[e].x & 255], 1);
    __syncthreads();
    int v = h[t];
    sc[t] = v;
    __syncthreads();
    for (int o = 1; o < 256; o <<= 1) {
        int u = (t >= o) ? sc[t - o] : 0;
        __syncthreads();
        sc[t] += u;
        __syncthreads();
    }
    int excl = sc[t] - v;
    int gd = bk * 256 + t;
    if (gd <= NN) rowptr[gd] = bs + excl;   // gd==NN lands on empty tail -> NE
    cur[t] = excl;
    __syncthreads();
    for (int e = bs + t; e < be; e += 256) {
        int2 p = temp[e];
        int pos = atomicAdd(&cur[p.x & 255], 1);
        col[bs + pos] = p.y;
    }
}

// y1b = pack_bf16(x @ W1' + c1): word w of node n = (ch w, ch w+32)
__global__ __launch_bounds__(256, 2) void k_gemm1(const float* __restrict__ x,
                                                  float* __restrict__ ws, int br) {
    const float* __restrict__ W1p = ws + W1P_OFF + br * CIN * COUT;
    const float* __restrict__ c1  = ws + C1_OFF + br * COUT;
    unsigned* __restrict__ y1b = (unsigned*)ws + Y1B_OFF;
    int lane = threadIdx.x & 63;
    int wave = (blockIdx.x * blockDim.x + threadIdx.x) >> 6;
    int nw   = (gridDim.x * blockDim.x) >> 6;
    float wk[CIN];
    #pragma unroll
    for (int k = 0; k < CIN; ++k) wk[k] = W1p[k * COUT + lane];
    float c1v = c1[lane];
    for (int n = wave; n < NN; n += nw) {
        const float* __restrict__ xr =
            x + (size_t)__builtin_amdgcn_readfirstlane(n) * CIN;
        float a0 = 0.f, a1 = 0.f, a2 = 0.f, a3 = 0.f;
        #pragma unroll
        for (int k = 0; k < CIN; k += 4) {
            a0 = fmaf(xr[k],     wk[k],     a0);
            a1 = fmaf(xr[k + 1], wk[k + 1], a1);
            a2 = fmaf(xr[k + 2], wk[k + 2], a2);
            a3 = fmaf(xr[k + 3], wk[k + 3], a3);
        }
        float v = (a0 + a1) + (a2 + a3) + c1v;
        float vhi = __shfl(v, (lane & 31) + 32);
        if (lane < 32) {
            unsigned w = bf16_rne(v) | (bf16_rne(vhi) << 16);
            y1b[(size_t)n * 32 + lane] = w;
        }
    }
}

// fused: t = y1[n] + sum_{src} y1[src] (paired bf16 gather: lanes 0-31 read
// src A's 128B row, lanes 32-63 read src B's -> 2 edges per instruction,
// no duplicate half-wave line requests); relu(t+b1) @ W2 + b2 -> out;
// accumulate output-BN stats
__global__ __launch_bounds__(256, 4) void k_gather_l2(const float* __restrict__ W2all,
                                                      const float* __restrict__ b1all,
                                                      const float* __restrict__ b2all,
                                                      float* __restrict__ out,
                                                      float* __restrict__ ws, int br) {
    const float* __restrict__ W2 = W2all + br * COUT * COUT;
    const unsigned* __restrict__ y1b = (const unsigned*)ws + Y1B_OFF;
    const int* __restrict__ rowptr = (const int*)ws + ROWPTR_OFF + br * (NN + 1);
    const int* __restrict__ col    = (const int*)ws + COL_OFF + br * NE;
    float* osum = ws + OSUM_OFF + br * COUT;
    float* osq  = ws + OSQ_OFF  + br * COUT;
    int lane = threadIdx.x & 63;
    int w32  = lane & 31;
    bool lo  = (lane < 32);
    unsigned hiMask = lo ? 0u : 1u;
    int wave = (blockIdx.x * blockDim.x + threadIdx.x) >> 6;
    int nw   = (gridDim.x * blockDim.x) >> 6;
    float w2k[COUT];
    #pragma unroll
    for (int j = 0; j < COUT; ++j) w2k[j] = W2[j * COUT + lane];
    float b1v = b1all[br * COUT + lane];
    float b2v = b2all[br * COUT + lane];
    float ls = 0.f, lss = 0.f;
#define XTR(w) __uint_as_float(hiMask ? ((w) & 0xFFFF0000u) : ((w) << 16))
    for (int n = wave; n < NN; n += nw) {
        int nn = __builtin_amdgcn_readfirstlane(n);
        int beg = rowptr[nn], end = rowptr[nn + 1];
        float a0 = XTR(y1b[(size_t)nn * 32 + w32]);
        float a1 = 0.f, a2 = 0.f, a3 = 0.f;
        int j = beg;
        // main: 4 paired gathers = 8 edges per iteration
        for (; j + 7 < end; j += 8) {
            int sa0 = lo ? col[j]     : col[j + 1];
            int sa1 = lo ? col[j + 2] : col[j + 3];
            int sa2 = lo ? col[j + 4] : col[j + 5];
            int sa3 = lo ? col[j + 6] : col[j + 7];
            unsigned u0 = y1b[(size_t)sa0 * 32 + w32];
            unsigned u1 = y1b[(size_t)sa1 * 32 + w32];
            unsigned u2 = y1b[(size_t)sa2 * 32 + w32];
            unsigned u3 = y1b[(size_t)sa3 * 32 + w32];
            unsigned v0 = __shfl_xor(u0, 32);
            unsigned v1 = __shfl_xor(u1, 32);
            unsigned v2 = __shfl_xor(u2, 32);
            unsigned v3 = __shfl_xor(u3, 32);
            a0 += XTR(u0) + XTR(v0);
            a1 += XTR(u1) + XTR(v1);
            a2 += XTR(u2) + XTR(v2);
            a3 += XTR(u3) + XTR(v3);
        }
        // pair tail
        for (; j + 1 < end; j += 2) {
            int sa = lo ? col[j] : col[j + 1];
            unsigned u = y1b[(size_t)sa * 32 + w32];
            unsigned v = __shfl_xor(u, 32);
            a0 += XTR(u) + XTR(v);
        }
        // odd single edge
        if (j < end) {
            unsigned u = y1b[(size_t)col[j] * 32 + w32];
            a0 += XTR(u);
        }
        float t1 = fmaxf((a0 + a1) + (a2 + a3) + b1v, 0.f);
        int t1i = __float_as_int(t1);
        float s0 = b2v, s1 = 0.f, s2 = 0.f, s3 = 0.f;
        #pragma unroll
        for (int k = 0; k < COUT; k += 4) {
            s0 = fmaf(__int_as_float(__builtin_amdgcn_readlane(t1i, k)),     w2k[k],     s0);
            s1 = fmaf(__int_as_float(__builtin_amdgcn_readlane(t1i, k + 1)), w2k[k + 1], s1);
            s2 = fmaf(__int_as_float(__builtin_amdgcn_readlane(t1i, k + 2)), w2k[k + 2], s2);
            s3 = fmaf(__int_as_float(__builtin_amdgcn_readlane(t1i, k + 3)), w2k[k + 3], s3);
        }
        float acc = (s0 + s1) + (s2 + s3);
        out[(size_t)nn * COUT + lane] = acc;
        ls += acc; lss += acc * acc;
    }
#undef XTR
    unsafeAtomicAdd(&osum[lane], ls);
    unsafeAtomicAdd(&osq[lane], lss);
}

__global__ void k_obn_final(const float* __restrict__ g, const float* __restrict__ b,
                            float* __restrict__ ws, int br) {
    int o = threadIdx.x;   // 64 threads
    float mu  = ws[OSUM_OFF + br * COUT + o] * (1.f / NN);
    float var = ws[OSQ_OFF  + br * COUT + o] * (1.f / NN) - mu * mu;
    float sc  = g[br * COUT + o] * rsqrtf(var + BN_EPS);
    ws[OBNS_OFF + br * COUT + o] = sc;
    ws[OBNB_OFF + br * COUT + o] = b[br * COUT + o] - mu * sc;
}

// y = tanh(sc[c]*h2 + sh[c]) in-place on d_out section
__global__ __launch_bounds__(256) void k_apply(float* __restrict__ out,
                                               const float* __restrict__ ws, int br) {
    const float* __restrict__ sc = ws + OBNS_OFF + br * COUT;
    const float* __restrict__ sh = ws + OBNB_OFF + br * COUT;
    int idx = blockIdx.x * blockDim.x + threadIdx.x;
    int stride = gridDim.x * blockDim.x;
    const int total = NN * COUT / 4;
    float4* o4 = (float4*)out;
    for (int v = idx; v < total; v += stride) {
        int c = (v & 15) * 4;
        float4 f = o4[v];
        f.x = tanhf(fmaf(f.x, sc[c],     sh[c]));
        f.y = tanhf(fmaf(f.y, sc[c + 1], sh[c + 1]));
        f.z = tanhf(fmaf(f.z, sc[c + 2], sh[c + 2]));
        f.w = tanhf(fmaf(f.w, sc[c + 3], sh[c + 3]));
        o4[v] = f;
    }
}

extern "C" void kernel_launch(void* const* d_in, const int* in_sizes, int n_in,
                              void* d_out, int out_size, void* d_ws, size_t ws_size,
                              hipStream_t stream) {
    const float* x   = (const float*)d_in[0];
    const int*   eip = (const int*)d_in[1];
    const int*   eis = (const int*)d_in[2];
    const int*   eiv = (const int*)d_in[3];
    const float* ig  = (const float*)d_in[4];
    const float* ib  = (const float*)d_in[5];
    const float* W1  = (const float*)d_in[6];
    const float* b1  = (const float*)d_in[7];
    const float* W2  = (const float*)d_in[8];
    const float* b2  = (const float*)d_in[9];
    const float* bng = (const float*)d_in[10];
    const float* bnb = (const float*)d_in[11];
    float* out = (float*)d_out;
    float* ws  = (float*)d_ws;
    int*   wsi = (int*)d_ws;

    hipMemsetAsync(ws + ZERO_OFF, 0, ZERO_CNT * sizeof(float), stream);

    k_in_stats<<<256, 256, 0, stream>>>(x, ws);
    k_in_finalize<<<1, 128, 0, stream>>>(ig, ib, ws);
    k_fold<<<96, 256, 0, stream>>>(W1, ws);
    k_c1<<<3, 64, 0, stream>>>(W1, ws);

    // two-level bucket sort -> CSR for all 3 branches (temp overlaps y1b;
    // all sort kernels complete before the first k_gemm1)
    k_sort_hist<<<dim3(NBLK1, 3), 256, 0, stream>>>(eip, eis, eiv, wsi);
    k_sort_scan<<<3, 1024, 0, stream>>>(wsi);
    k_sort_scatter<<<dim3(NBLK1, 3), 256, 0, stream>>>(eip, eis, eiv, wsi);
    k_bucket<<<dim3(NB, 3), 256, 0, stream>>>(wsi);

    for (int br = 0; br < 3; ++br) {
        k_gemm1<<<1024, 256, 0, stream>>>(x, ws, br);
        k_gather_l2<<<2048, 256, 0, stream>>>(W2, b1, b2,
                                              out + (size_t)br * NN * COUT, ws, br);
        k_obn_final<<<1, 64, 0, stream>>>(bng, bnb, ws, br);
        k_apply<<<2048, 256, 0, stream>>>(out + (size_t)br * NN * COUT, ws, br);
    }
}